// Round 8
// baseline (1847.457 us; speedup 1.0000x reference)
//
#include <hip/hip_runtime.h>
#include <cstdio>

#define DIN   1024
#define DHID  4096
#define DOUT  1024
#define NEXP  16
#define NTOK  8192
#define NPAIR (NTOK * 2)
#define PADMAX 20480          // 16384 + 16*255 rounded up to 256
#define MAXTILES 80           // max sum of per-expert ceil(cnt/256)

typedef _Float16 h8 __attribute__((ext_vector_type(8)));
typedef _Float16 h4 __attribute__((ext_vector_type(4)));
typedef float    f4 __attribute__((ext_vector_type(4)));

// ctrl[] int indices
#define C_CNT  0    // [16] per-expert pair counts
#define C_POFF 16   // [16] padded segment offsets
#define C_CUR  32   // [16] assignment cursors
#define C_NT   48   // total tiles
#define C_TE   64   // [80] tile -> expert
#define C_TP   256  // [80] tile -> p0 (padded row start)

__device__ __forceinline__ void async16(const void* g, void* l) {
  __builtin_amdgcn_global_load_lds((const __attribute__((address_space(1))) void*)g,
                                   (__attribute__((address_space(3))) void*)l, 16, 0, 0);
}

// ---- init: zero out, convert x->fp16, default perm, zero ctrl ----
__global__ void k_init(float* __restrict__ out, const float* __restrict__ x,
                       _Float16* __restrict__ x16, int* __restrict__ ptok,
                       float* __restrict__ pw, int* __restrict__ ctrl) {
  int i = blockIdx.x * 256 + threadIdx.x;           // 2,097,152 threads
  ((f4*)out)[i] = (f4){0.f, 0.f, 0.f, 0.f};
  float4 v = ((const float4*)x)[i];
  h4 hv = {(_Float16)v.x, (_Float16)v.y, (_Float16)v.z, (_Float16)v.w};
  ((h4*)x16)[i] = hv;
  if (i < PADMAX) { ptok[i] = 0; pw[i] = 0.f; }
  if (i < 1024) ctrl[i] = 0;
}

// ---- gating: logits, top-2, softmax weights, counts. 1 wave/token ----
__global__ void k_gate(const float* __restrict__ x, const float* __restrict__ wg,
                       int* __restrict__ te, float* __restrict__ tw,
                       int* __restrict__ ctrl) {
  int t = blockIdx.x * 4 + (threadIdx.x >> 6);
  int l = threadIdx.x & 63;
  const float* xr = x + (long)t * DIN;
  float acc[NEXP];
#pragma unroll
  for (int e = 0; e < NEXP; ++e) acc[e] = 0.f;
  for (int k = l; k < DIN; k += 64) {
    float xv = xr[k];
    const float4* wr = (const float4*)(wg + (long)k * NEXP);
    float4 a = wr[0], b = wr[1], c = wr[2], d = wr[3];
    acc[0]  += xv * a.x; acc[1]  += xv * a.y; acc[2]  += xv * a.z; acc[3]  += xv * a.w;
    acc[4]  += xv * b.x; acc[5]  += xv * b.y; acc[6]  += xv * b.z; acc[7]  += xv * b.w;
    acc[8]  += xv * c.x; acc[9]  += xv * c.y; acc[10] += xv * c.z; acc[11] += xv * c.w;
    acc[12] += xv * d.x; acc[13] += xv * d.y; acc[14] += xv * d.z; acc[15] += xv * d.w;
  }
#pragma unroll
  for (int off = 32; off > 0; off >>= 1) {
#pragma unroll
    for (int e = 0; e < NEXP; ++e) acc[e] += __shfl_xor(acc[e], off, 64);
  }
  if (l == 0) {
    float v0 = -1e30f; int e0 = 0;
#pragma unroll
    for (int e = 0; e < NEXP; ++e) if (acc[e] > v0) { v0 = acc[e]; e0 = e; }
    float v1 = -1e30f; int e1 = 0;
#pragma unroll
    for (int e = 0; e < NEXP; ++e) if (e != e0 && acc[e] > v1) { v1 = acc[e]; e1 = e; }
    float d = expf(v1 - v0);
    float den = 1.f / (1.f + d);
    te[2 * t] = e0;     tw[2 * t] = den;       // w0 (top-1)
    te[2 * t + 1] = e1; tw[2 * t + 1] = d * den;
    atomicAdd(&ctrl[C_CNT + e0], 1);
    atomicAdd(&ctrl[C_CNT + e1], 1);
  }
}

// ---- scan: padded offsets (256-granular), cursors, tile table ----
__global__ void k_scan(int* __restrict__ ctrl) {
  __shared__ int sOff[NEXP], sT0[NEXP], sTiles[NEXP];
  int tid = threadIdx.x;
  if (tid == 0) {
    int off = 0, nt = 0;
    for (int e = 0; e < NEXP; ++e) {
      int c = ctrl[C_CNT + e];
      int tiles = (c + 255) >> 8;
      ctrl[C_POFF + e] = off;
      ctrl[C_CUR + e] = off;
      sOff[e] = off; sT0[e] = nt; sTiles[e] = tiles;
      nt += tiles;
      off += tiles * 256;
    }
    ctrl[C_NT] = nt;
  }
  __syncthreads();
  int nt = sT0[NEXP - 1] + sTiles[NEXP - 1];
  for (int j = tid; j < nt; j += blockDim.x) {
    int e = 0;
#pragma unroll
    for (int k = 1; k < NEXP; ++k) if (j >= sT0[k]) e = k;
    ctrl[C_TE + j] = e;
    ctrl[C_TP + j] = sOff[e] + (j - sT0[e]) * 256;
  }
}

// ---- assign: fill permuted pair arrays ----
__global__ void k_assign(const int* __restrict__ te, const float* __restrict__ tw,
                         int* __restrict__ ctrl, int* __restrict__ ptok,
                         float* __restrict__ pw) {
  int t = blockIdx.x * 256 + threadIdx.x;
#pragma unroll
  for (int s = 0; s < 2; ++s) {
    int e = te[2 * t + s];
    int pos = atomicAdd(&ctrl[C_CUR + e], 1);
    ptok[pos] = t;
    pw[pos] = tw[2 * t + s];
  }
}

// ---- transpose+convert v3: W [E][R][C] fp32 -> out [E][C][R] fp16 ----
// Classic padded transpose, bank-verified:
//   tileT[64][65] fp32. Phase1: float4 global load, 4 scalar ds_write_b32 at
//   bank (4*(l&15)+65j+r) mod 32 -> exact 2-way (free, m136).
//   Phase2: 16 scalar b32 row-reads (banks c+rb+k -> 2-way free), cvt, 2x h8.
__global__ void k_transpose(const float* __restrict__ W, _Float16* __restrict__ out,
                            int R, int C) {
  __shared__ float tileT[64][65];
  int e = blockIdx.z;
  const float* Wb = W + ((long)e * R + blockIdx.x * 64) * C + blockIdx.y * 64;
  _Float16* ob = out + ((long)e * C + blockIdx.y * 64) * R + blockIdx.x * 64;
  int t = threadIdx.x;
  int r0 = t >> 4;            // 0..15
  int c4 = (t & 15) * 4;
#pragma unroll
  for (int i = 0; i < 4; ++i) {
    int r = r0 + i * 16;
    float4 v = *(const float4*)(Wb + (long)r * C + c4);
    tileT[c4 + 0][r] = v.x;
    tileT[c4 + 1][r] = v.y;
    tileT[c4 + 2][r] = v.z;
    tileT[c4 + 3][r] = v.w;
  }
  __syncthreads();
  int c = t >> 2;             // 0..63
  int rb = (t & 3) * 16;
  float f[16];
#pragma unroll
  for (int k = 0; k < 16; ++k) f[k] = tileT[c][rb + k];
#pragma unroll
  for (int k = 0; k < 2; ++k) {
    h8 hv = {(_Float16)f[k * 8 + 0], (_Float16)f[k * 8 + 1],
             (_Float16)f[k * 8 + 2], (_Float16)f[k * 8 + 3],
             (_Float16)f[k * 8 + 4], (_Float16)f[k * 8 + 5],
             (_Float16)f[k * 8 + 6], (_Float16)f[k * 8 + 7]};
    *(h8*)(ob + (long)c * R + rb + k * 8) = hv;
  }
}

// ---- grouped GEMM: 256x256 tile, BK=64, 8 waves (2Mx4N) ----
// 1-barrier-per-K-step pipeline: stage(t+1 -> buf^1) issued at step top (8x
// async16); all 24 ds_reads issued (A0->af, B0->bf0, B1->bf1, A1->af2); 4 MFMA
// quadrants in dependency order. Compiler inserts counted lgkmcnt between each
// read group and its consuming MFMA (m97-verified) -> LDS drain overlaps MFMA.
// vmcnt(0)+s_barrier once per step (stage issued a full step before the wait).
// Sync: reads of buf d are consumed by MFMAs before each wave's barrier
// arrival -> staging into d at step t+1 is race-free.
// nb-FASTEST wid decode (R7: FETCH 453->183MB) + bijective XCD chunk swizzle.
template<int KD, int ND, int G1>
__global__ __launch_bounds__(512, 2)
void k_gemm(const _Float16* __restrict__ A, const _Float16* __restrict__ Wt,
            const float* __restrict__ bias, const int* __restrict__ ctrl,
            const int* __restrict__ ptok, const float* __restrict__ pw,
            _Float16* __restrict__ Hout, float* __restrict__ out) {
  __shared__ __align__(16) _Float16 sm[65536];   // 128 KB

  constexpr int NB = ND / 256;
  constexpr int NW = NB * MAXTILES;
  constexpr int QX = NW / 8;                     // chunk per XCD
  int bid = blockIdx.x;
  int wid = (bid & 7) * QX + (bid >> 3);         // bijective XCD chunk swizzle
  int nb = wid % NB;                             // nb-FASTEST (A-panel locality)
  int mt = wid / NB;

  if (mt >= ctrl[C_NT]) return;
  int e  = ctrl[C_TE + mt];
  int p0 = ctrl[C_TP + mt];
  int n0 = nb * 256;
  int tid = threadIdx.x;
  int w = tid >> 6, l = tid & 63;
  int wm = w & 1, wn = w >> 1;           // 2 M-warps x 4 N-warps
  int ln15 = l & 15, lq = l >> 4;

  // ---- staging pointers: per (tensor, half, slot j) ----
  const _Float16* agp[4];   // [half*2+j]
  const _Float16* bgp[4];
#pragma unroll
  for (int h = 0; h < 2; ++h)
#pragma unroll
    for (int j = 0; j < 2; ++j) {
      int r = (w * 2 + j) * 8 + (l >> 3);          // row in half, 0..127
      int c = (l & 7) ^ (r & 7);
      long arow = G1 ? (long)ptok[p0 + h * 128 + r] : (long)(p0 + h * 128 + r);
      agp[h * 2 + j] = A + arow * KD + c * 8;
      bgp[h * 2 + j] = Wt + ((long)e * ND + n0 + h * 128 + r) * KD + c * 8;
    }

  // half ids: 0=A0 1=B0 2=A1 3=B1
  auto stageH = [&](int t, int half) {
    _Float16* dst = sm + (t & 1) * 32768 + (half & 1) * 16384 + (half >> 1) * 8192
                    + w * 1024;
    long koff = (long)t * 64;
    const _Float16* const* gp = (half & 1) ? bgp : agp;
#pragma unroll
    for (int j = 0; j < 2; ++j)
      async16(gp[(half >> 1) * 2 + j] + koff, dst + j * 512);
  };

  f4 acc[2][4][2][2];
#pragma unroll
  for (int mq = 0; mq < 2; ++mq)
#pragma unroll
    for (int i = 0; i < 4; ++i)
#pragma unroll
      for (int nq = 0; nq < 2; ++nq)
#pragma unroll
        for (int j = 0; j < 2; ++j) acc[mq][i][nq][j] = (f4){0.f, 0.f, 0.f, 0.f};

  h8 af[8], af2[8], bf0[4], bf1[4];

  auto readA = [&](int d, int mq, h8* dst) {  // 8 x ds_read_b128
    const _Float16* Ab = sm + d * 32768 + mq * 8192;
#pragma unroll
    for (int i = 0; i < 4; ++i) {
      int rh = wm * 64 + i * 16 + ln15;
#pragma unroll
      for (int ks = 0; ks < 2; ++ks)
        dst[i * 2 + ks] = *(const h8*)&Ab[rh * 64 + (((ks * 4 + lq)) ^ (rh & 7)) * 8];
    }
  };
  auto readB = [&](int d, int nq, h8* bf) {   // 4 x ds_read_b128
    const _Float16* Bb = sm + d * 32768 + 16384 + nq * 8192;
#pragma unroll
    for (int j = 0; j < 2; ++j) {
      int rh = wn * 32 + j * 16 + ln15;
#pragma unroll
      for (int ks = 0; ks < 2; ++ks)
        bf[j * 2 + ks] = *(const h8*)&Bb[rh * 64 + (((ks * 4 + lq)) ^ (rh & 7)) * 8];
    }
  };
  auto mfmaQ = [&](int mq, int nq, const h8* a, const h8* bf) {  // 16 MFMA
    __builtin_amdgcn_s_setprio(1);
#pragma unroll
    for (int ks = 0; ks < 2; ++ks)
#pragma unroll
      for (int i = 0; i < 4; ++i)
#pragma unroll
        for (int j = 0; j < 2; ++j)
          acc[mq][i][nq][j] = __builtin_amdgcn_mfma_f32_16x16x32_f16(
              a[i * 2 + ks], bf[j * 2 + ks], acc[mq][i][nq][j], 0, 0, 0);
    __builtin_amdgcn_s_setprio(0);
  };

  constexpr int KSTEPS = KD / 64;      // 16 (G1) or 64 (G2)

  // prologue: stage tile0 into buf0, drain, sync
  stageH(0, 0); stageH(0, 1); stageH(0, 2); stageH(0, 3);
  asm volatile("s_waitcnt vmcnt(0)" ::: "memory");
  __builtin_amdgcn_s_barrier();

#pragma unroll 2
  for (int t = 0; t < KSTEPS; ++t) {
    int d = t & 1;
    if (t + 1 < KSTEPS) {                       // prefetch t+1 -> buf d^1
      stageH(t + 1, 0); stageH(t + 1, 1); stageH(t + 1, 2); stageH(t + 1, 3);
    }
    readA(d, 0, af);
    readB(d, 0, bf0);
    readB(d, 1, bf1);
    readA(d, 1, af2);
    mfmaQ(0, 0, af,  bf0);
    mfmaQ(0, 1, af,  bf1);
    mfmaQ(1, 1, af2, bf1);
    mfmaQ(1, 0, af2, bf0);
    if (t + 1 < KSTEPS) asm volatile("s_waitcnt vmcnt(0)" ::: "memory");
    __builtin_amdgcn_s_barrier();
  }

  // ---- epilogue ----
  float bj[2][2];
#pragma unroll
  for (int nq = 0; nq < 2; ++nq)
#pragma unroll
    for (int j = 0; j < 2; ++j)
      bj[nq][j] = bias[e * ND + n0 + nq * 128 + wn * 32 + j * 16 + ln15];

  if (G1) {
    // LDS-bounce (reuse sm): two 128-row halves, [128][264] fp16 padded
    _Float16* cs = sm;
#pragma unroll
    for (int mq = 0; mq < 2; ++mq) {
      if (mq) __syncthreads();
#pragma unroll
      for (int i = 0; i < 4; ++i)
#pragma unroll
        for (int reg = 0; reg < 4; ++reg) {
          int row = wm * 64 + i * 16 + lq * 4 + reg;
#pragma unroll
          for (int nq = 0; nq < 2; ++nq)
#pragma unroll
            for (int j = 0; j < 2; ++j)
              cs[row * 264 + nq * 128 + wn * 32 + j * 16 + ln15] =
                  (_Float16)fmaxf(acc[mq][i][nq][j][reg] + bj[nq][j], 0.f);
        }
      __syncthreads();
#pragma unroll
      for (int p = 0; p < 8; ++p) {
        int idx = p * 512 + tid;          // 128 rows x 32 h8-chunks
        int row = idx >> 5, ch = idx & 31;
        *(h8*)(Hout + (long)(p0 + mq * 128 + row) * DHID + n0 + ch * 8) =
            *(const h8*)&cs[row * 264 + ch * 8];
      }
    }
  } else {
#pragma unroll
    for (int mq = 0; mq < 2; ++mq)
#pragma unroll
      for (int i = 0; i < 4; ++i)
#pragma unroll
        for (int reg = 0; reg < 4; ++reg) {
          int p = p0 + mq * 128 + wm * 64 + i * 16 + lq * 4 + reg;
          float wgt = pw[p];
          if (wgt != 0.f) {
            int tk = ptok[p];
            float* orow = out + (long)tk * DOUT + n0;
#pragma unroll
            for (int nq = 0; nq < 2; ++nq)
#pragma unroll
              for (int j = 0; j < 2; ++j)
                atomicAdd(&orow[nq * 128 + wn * 32 + j * 16 + ln15],
                          wgt * (acc[mq][i][nq][j][reg] + bj[nq][j]));
          }
        }
  }
}

extern "C" void kernel_launch(void* const* d_in, const int* in_sizes, int n_in,
                              void* d_out, int out_size, void* d_ws, size_t ws_size,
                              hipStream_t stream) {
  const float* x  = (const float*)d_in[0];
  const float* Wg = (const float*)d_in[1];
  const float* W1 = (const float*)d_in[2];
  const float* b1 = (const float*)d_in[3];
  const float* W2 = (const float*)d_in[4];
  const float* b2 = (const float*)d_in[5];
  float* out = (float*)d_out;
  char* ws = (char*)d_ws;

  size_t WT_OFF = 0;                                   // fp16 W^T (reused W1 then W2)
  size_t H_OFF  = WT_OFF + (size_t)NEXP * DHID * DIN * 2;   // 134,217,728
  size_t X_OFF  = H_OFF  + (size_t)PADMAX * DHID * 2;       // +167,772,160
  size_t TE_OFF = X_OFF  + (size_t)NTOK * DIN * 2;          // +16,777,216
  size_t TW_OFF = TE_OFF + (size_t)NPAIR * 4;
  size_t PT_OFF = TW_OFF + (size_t)NPAIR * 4;
  size_t PW_OFF = PT_OFF + (size_t)PADMAX * 4;
  size_t CT_OFF = PW_OFF + (size_t)PADMAX * 4;
  size_t END    = CT_OFF + 4096;
  if (ws_size < END) {
    fprintf(stderr, "kernel_launch: ws too small (%zu < %zu)\n", ws_size, END);
    return;
  }
  _Float16* Wt  = (_Float16*)(ws + WT_OFF);
  _Float16* H   = (_Float16*)(ws + H_OFF);
  _Float16* x16 = (_Float16*)(ws + X_OFF);
  int*   te   = (int*)(ws + TE_OFF);
  float* tw   = (float*)(ws + TW_OFF);
  int*   pt   = (int*)(ws + PT_OFF);
  float* pw   = (float*)(ws + PW_OFF);
  int*   ctrl = (int*)(ws + CT_OFF);

  k_init<<<NTOK * DIN / (256 * 4), 256, 0, stream>>>(out, x, x16, pt, pw, ctrl);
  k_gate<<<NTOK / 4, 256, 0, stream>>>(x, Wg, te, tw, ctrl);
  k_scan<<<1, 256, 0, stream>>>(ctrl);
  k_assign<<<NTOK / 256, 256, 0, stream>>>(te, tw, ctrl, pt, pw);

  // W1 [E][1024][4096] -> Wt [E][4096][1024] fp16
  k_transpose<<<dim3(DIN / 64, DHID / 64, NEXP), 256, 0, stream>>>(W1, Wt, DIN, DHID);
  // G1: works = 80 mt x 16 nb (nb-fastest)
  k_gemm<DIN, DHID, 1><<<dim3((DHID / 256) * MAXTILES), 512, 0, stream>>>(
      x16, Wt, b1, ctrl, pt, pw, H, nullptr);

  // W2 [E][4096][1024] -> Wt [E][1024][4096] fp16 (region reuse; stream-ordered)
  k_transpose<<<dim3(DHID / 64, DOUT / 64, NEXP), 256, 0, stream>>>(W2, Wt, DHID, DOUT);
  // G2: works = 80 mt x 4 nb (nb-fastest)
  k_gemm<DHID, DOUT, 0><<<dim3((DOUT / 256) * MAXTILES), 512, 0, stream>>>(
      H, Wt, b2, ctrl, pt, pw, nullptr, out);
}

// Round 9
// 1292.207 us; speedup vs baseline: 1.4297x; 1.4297x over previous
//
#include <hip/hip_runtime.h>
#include <cstdio>

#define DIN   1024
#define DHID  4096
#define DOUT  1024
#define NEXP  16
#define NTOK  8192
#define NPAIR (NTOK * 2)
#define PADMAX 20480          // 16384 + 16*255 rounded up to 256
#define MAXTILES 80           // max sum of per-expert ceil(cnt/256)

typedef _Float16 h8 __attribute__((ext_vector_type(8)));
typedef _Float16 h4 __attribute__((ext_vector_type(4)));
typedef float    f4 __attribute__((ext_vector_type(4)));

// ctrl[] int indices
#define C_CNT  0    // [16] per-expert pair counts
#define C_POFF 16   // [16] padded segment offsets
#define C_CUR  32   // [16] assignment cursors
#define C_NT   48   // total tiles
#define C_TE   64   // [80] tile -> expert
#define C_TP   256  // [80] tile -> p0 (padded row start)

__device__ __forceinline__ void async16(const void* g, void* l) {
  __builtin_amdgcn_global_load_lds((const __attribute__((address_space(1))) void*)g,
                                   (__attribute__((address_space(3))) void*)l, 16, 0, 0);
}

// ---- init: zero out, convert x->fp16, default perm, zero ctrl ----
__global__ void k_init(float* __restrict__ out, const float* __restrict__ x,
                       _Float16* __restrict__ x16, int* __restrict__ ptok,
                       float* __restrict__ pw, int* __restrict__ ctrl) {
  int i = blockIdx.x * 256 + threadIdx.x;           // 2,097,152 threads
  ((f4*)out)[i] = (f4){0.f, 0.f, 0.f, 0.f};
  float4 v = ((const float4*)x)[i];
  h4 hv = {(_Float16)v.x, (_Float16)v.y, (_Float16)v.z, (_Float16)v.w};
  ((h4*)x16)[i] = hv;
  if (i < PADMAX) { ptok[i] = 0; pw[i] = 0.f; }
  if (i < 1024) ctrl[i] = 0;
}

// ---- gating: logits, top-2, softmax weights, counts. 1 wave/token ----
__global__ void k_gate(const float* __restrict__ x, const float* __restrict__ wg,
                       int* __restrict__ te, float* __restrict__ tw,
                       int* __restrict__ ctrl) {
  int t = blockIdx.x * 4 + (threadIdx.x >> 6);
  int l = threadIdx.x & 63;
  const float* xr = x + (long)t * DIN;
  float acc[NEXP];
#pragma unroll
  for (int e = 0; e < NEXP; ++e) acc[e] = 0.f;
  for (int k = l; k < DIN; k += 64) {
    float xv = xr[k];
    const float4* wr = (const float4*)(wg + (long)k * NEXP);
    float4 a = wr[0], b = wr[1], c = wr[2], d = wr[3];
    acc[0]  += xv * a.x; acc[1]  += xv * a.y; acc[2]  += xv * a.z; acc[3]  += xv * a.w;
    acc[4]  += xv * b.x; acc[5]  += xv * b.y; acc[6]  += xv * b.z; acc[7]  += xv * b.w;
    acc[8]  += xv * c.x; acc[9]  += xv * c.y; acc[10] += xv * c.z; acc[11] += xv * c.w;
    acc[12] += xv * d.x; acc[13] += xv * d.y; acc[14] += xv * d.z; acc[15] += xv * d.w;
  }
#pragma unroll
  for (int off = 32; off > 0; off >>= 1) {
#pragma unroll
    for (int e = 0; e < NEXP; ++e) acc[e] += __shfl_xor(acc[e], off, 64);
  }
  if (l == 0) {
    float v0 = -1e30f; int e0 = 0;
#pragma unroll
    for (int e = 0; e < NEXP; ++e) if (acc[e] > v0) { v0 = acc[e]; e0 = e; }
    float v1 = -1e30f; int e1 = 0;
#pragma unroll
    for (int e = 0; e < NEXP; ++e) if (e != e0 && acc[e] > v1) { v1 = acc[e]; e1 = e; }
    float d = expf(v1 - v0);
    float den = 1.f / (1.f + d);
    te[2 * t] = e0;     tw[2 * t] = den;       // w0 (top-1)
    te[2 * t + 1] = e1; tw[2 * t + 1] = d * den;
    atomicAdd(&ctrl[C_CNT + e0], 1);
    atomicAdd(&ctrl[C_CNT + e1], 1);
  }
}

// ---- scan: padded offsets (256-granular), cursors, tile table ----
__global__ void k_scan(int* __restrict__ ctrl) {
  __shared__ int sOff[NEXP], sT0[NEXP], sTiles[NEXP];
  int tid = threadIdx.x;
  if (tid == 0) {
    int off = 0, nt = 0;
    for (int e = 0; e < NEXP; ++e) {
      int c = ctrl[C_CNT + e];
      int tiles = (c + 255) >> 8;
      ctrl[C_POFF + e] = off;
      ctrl[C_CUR + e] = off;
      sOff[e] = off; sT0[e] = nt; sTiles[e] = tiles;
      nt += tiles;
      off += tiles * 256;
    }
    ctrl[C_NT] = nt;
  }
  __syncthreads();
  int nt = sT0[NEXP - 1] + sTiles[NEXP - 1];
  for (int j = tid; j < nt; j += blockDim.x) {
    int e = 0;
#pragma unroll
    for (int k = 1; k < NEXP; ++k) if (j >= sT0[k]) e = k;
    ctrl[C_TE + j] = e;
    ctrl[C_TP + j] = sOff[e] + (j - sT0[e]) * 256;
  }
}

// ---- assign: fill permuted pair arrays ----
__global__ void k_assign(const int* __restrict__ te, const float* __restrict__ tw,
                         int* __restrict__ ctrl, int* __restrict__ ptok,
                         float* __restrict__ pw) {
  int t = blockIdx.x * 256 + threadIdx.x;
#pragma unroll
  for (int s = 0; s < 2; ++s) {
    int e = te[2 * t + s];
    int pos = atomicAdd(&ctrl[C_CUR + e], 1);
    ptok[pos] = t;
    pw[pos] = tw[2 * t + s];
  }
}

// ---- transpose+convert v3: W [E][R][C] fp32 -> out [E][C][R] fp16 ----
// Classic padded transpose, bank-verified 2-way (free, m136) on both phases.
__global__ void k_transpose(const float* __restrict__ W, _Float16* __restrict__ out,
                            int R, int C) {
  __shared__ float tileT[64][65];
  int e = blockIdx.z;
  const float* Wb = W + ((long)e * R + blockIdx.x * 64) * C + blockIdx.y * 64;
  _Float16* ob = out + ((long)e * C + blockIdx.y * 64) * R + blockIdx.x * 64;
  int t = threadIdx.x;
  int r0 = t >> 4;            // 0..15
  int c4 = (t & 15) * 4;
#pragma unroll
  for (int i = 0; i < 4; ++i) {
    int r = r0 + i * 16;
    float4 v = *(const float4*)(Wb + (long)r * C + c4);
    tileT[c4 + 0][r] = v.x;
    tileT[c4 + 1][r] = v.y;
    tileT[c4 + 2][r] = v.z;
    tileT[c4 + 3][r] = v.w;
  }
  __syncthreads();
  int c = t >> 2;             // 0..63
  int rb = (t & 3) * 16;
  float f[16];
#pragma unroll
  for (int k = 0; k < 16; ++k) f[k] = tileT[c][rb + k];
#pragma unroll
  for (int k = 0; k < 2; ++k) {
    h8 hv = {(_Float16)f[k * 8 + 0], (_Float16)f[k * 8 + 1],
             (_Float16)f[k * 8 + 2], (_Float16)f[k * 8 + 3],
             (_Float16)f[k * 8 + 4], (_Float16)f[k * 8 + 5],
             (_Float16)f[k * 8 + 6], (_Float16)f[k * 8 + 7]};
    *(h8*)(ob + (long)c * R + rb + k * 8) = hv;
  }
}

// ---- grouped GEMM: 256x256 tile, BK=64, 8 waves (2Mx4N) ----
// ks-SLICED merged loop (spill-hardened R8):
//   step top: stage(t+1 -> buf d^1), 8x async16.
//   then TWO K=32 slices in a '#pragma unroll 1' loop (forces register reuse,
//   no cross-slice renaming): each slice = 12 ds_read_b128 (a0[4],a1[4],
//   b0[2],b1[2] = 48 VGPR) + 32 MFMA. No lgkmcnt(0) in the loop -> compiler's
//   counted lgkm overlaps LDS drain with MFMA (the R7 serialization fix).
//   One vmcnt(0)+s_barrier per K-step. Peak live ~ acc64+frag48+off8 < 128.
// Addressing: 8 int element-offsets (aoff/boff) + uniform bases (was 16 ptr
// VGPRs). nb-FASTEST wid decode (R7: FETCH 453->183MB) + XCD chunk swizzle.
template<int KD, int ND, int G1>
__global__ __launch_bounds__(512, 2)
void k_gemm(const _Float16* __restrict__ A, const _Float16* __restrict__ Wt,
            const float* __restrict__ bias, const int* __restrict__ ctrl,
            const int* __restrict__ ptok, const float* __restrict__ pw,
            _Float16* __restrict__ Hout, float* __restrict__ out) {
  __shared__ __align__(16) _Float16 sm[65536];   // 128 KB

  constexpr int NB = ND / 256;
  constexpr int NW = NB * MAXTILES;
  constexpr int QX = NW / 8;                     // chunk per XCD
  int bid = blockIdx.x;
  int wid = (bid & 7) * QX + (bid >> 3);         // bijective XCD chunk swizzle
  int nb = wid % NB;                             // nb-FASTEST (A-panel locality)
  int mt = wid / NB;

  if (mt >= ctrl[C_NT]) return;
  int e  = ctrl[C_TE + mt];
  int p0 = ctrl[C_TP + mt];
  int n0 = nb * 256;
  int tid = threadIdx.x;
  int w = tid >> 6, l = tid & 63;
  int wm = w & 1, wn = w >> 1;           // 2 M-warps x 4 N-warps
  int ln15 = l & 15, lq = l >> 4;

  // ---- staging offsets (int elements): [half][slot] ----
  int aoff[2][2], boff[2][2];
#pragma unroll
  for (int h = 0; h < 2; ++h)
#pragma unroll
    for (int j = 0; j < 2; ++j) {
      int r = (w * 2 + j) * 8 + (l >> 3);          // row in half, 0..127
      int c = (l & 7) ^ (r & 7);
      int arow = G1 ? ptok[p0 + h * 128 + r] : (p0 + h * 128 + r);
      aoff[h][j] = arow * KD + c * 8;
      boff[h][j] = (e * ND + n0 + h * 128 + r) * KD + c * 8;
    }

  // half ids: 0=A0 1=B0 2=A1 3=B1
  auto stageH = [&](int t, int half) {
    _Float16* dst = sm + (t & 1) * 32768 + (half & 1) * 16384 + (half >> 1) * 8192
                    + w * 1024;
    int koff = t * 64;
    const _Float16* base = (half & 1) ? Wt : A;
    if (half & 1) {
      async16(base + boff[half >> 1][0] + koff, dst);
      async16(base + boff[half >> 1][1] + koff, dst + 512);
    } else {
      async16(base + aoff[half >> 1][0] + koff, dst);
      async16(base + aoff[half >> 1][1] + koff, dst + 512);
    }
  };

  f4 acc[2][4][2][2];
#pragma unroll
  for (int mq = 0; mq < 2; ++mq)
#pragma unroll
    for (int i = 0; i < 4; ++i)
#pragma unroll
      for (int nq = 0; nq < 2; ++nq)
#pragma unroll
        for (int j = 0; j < 2; ++j) acc[mq][i][nq][j] = (f4){0.f, 0.f, 0.f, 0.f};

  constexpr int KSTEPS = KD / 64;      // 16 (G1) or 64 (G2)

  // prologue: stage tile0 into buf0, drain, sync
  stageH(0, 0); stageH(0, 1); stageH(0, 2); stageH(0, 3);
  asm volatile("s_waitcnt vmcnt(0)" ::: "memory");
  __builtin_amdgcn_s_barrier();

#pragma unroll 2
  for (int t = 0; t < KSTEPS; ++t) {
    int d = t & 1;
    if (t + 1 < KSTEPS) {                       // prefetch t+1 -> buf d^1
      stageH(t + 1, 0); stageH(t + 1, 1); stageH(t + 1, 2); stageH(t + 1, 3);
    }
    const _Float16* Ab0 = sm + d * 32768;
    const _Float16* Ab1 = Ab0 + 8192;
    const _Float16* Bb0 = Ab0 + 16384;
    const _Float16* Bb1 = Ab0 + 24576;
#pragma unroll 1
    for (int ks = 0; ks < 2; ++ks) {            // two K=32 slices, regs reused
      h8 a0[4], a1[4], b0[2], b1[2];
      int kq = ks * 4 + lq;
#pragma unroll
      for (int i = 0; i < 4; ++i) {
        int rh = wm * 64 + i * 16 + ln15;
        int co = (kq ^ (rh & 7)) * 8;
        a0[i] = *(const h8*)&Ab0[rh * 64 + co];
        a1[i] = *(const h8*)&Ab1[rh * 64 + co];
      }
#pragma unroll
      for (int j = 0; j < 2; ++j) {
        int rh = wn * 32 + j * 16 + ln15;
        int co = (kq ^ (rh & 7)) * 8;
        b0[j] = *(const h8*)&Bb0[rh * 64 + co];
        b1[j] = *(const h8*)&Bb1[rh * 64 + co];
      }
      __builtin_amdgcn_s_setprio(1);
#pragma unroll
      for (int i = 0; i < 4; ++i)
#pragma unroll
        for (int j = 0; j < 2; ++j) {
          acc[0][i][0][j] = __builtin_amdgcn_mfma_f32_16x16x32_f16(
              a0[i], b0[j], acc[0][i][0][j], 0, 0, 0);
          acc[0][i][1][j] = __builtin_amdgcn_mfma_f32_16x16x32_f16(
              a0[i], b1[j], acc[0][i][1][j], 0, 0, 0);
          acc[1][i][1][j] = __builtin_amdgcn_mfma_f32_16x16x32_f16(
              a1[i], b1[j], acc[1][i][1][j], 0, 0, 0);
          acc[1][i][0][j] = __builtin_amdgcn_mfma_f32_16x16x32_f16(
              a1[i], b0[j], acc[1][i][0][j], 0, 0, 0);
        }
      __builtin_amdgcn_s_setprio(0);
    }
    if (t + 1 < KSTEPS) asm volatile("s_waitcnt vmcnt(0)" ::: "memory");
    __builtin_amdgcn_s_barrier();
  }

  // ---- epilogue ----
  float bj[2][2];
#pragma unroll
  for (int nq = 0; nq < 2; ++nq)
#pragma unroll
    for (int j = 0; j < 2; ++j)
      bj[nq][j] = bias[e * ND + n0 + nq * 128 + wn * 32 + j * 16 + ln15];

  if (G1) {
    // LDS-bounce (reuse sm): two 128-row halves, [128][264] fp16 padded
    _Float16* cs = sm;
#pragma unroll
    for (int mq = 0; mq < 2; ++mq) {
      if (mq) __syncthreads();
#pragma unroll
      for (int i = 0; i < 4; ++i)
#pragma unroll
        for (int reg = 0; reg < 4; ++reg) {
          int row = wm * 64 + i * 16 + lq * 4 + reg;
#pragma unroll
          for (int nq = 0; nq < 2; ++nq)
#pragma unroll
            for (int j = 0; j < 2; ++j)
              cs[row * 264 + nq * 128 + wn * 32 + j * 16 + ln15] =
                  (_Float16)fmaxf(acc[mq][i][nq][j][reg] + bj[nq][j], 0.f);
        }
      __syncthreads();
#pragma unroll
      for (int p = 0; p < 8; ++p) {
        int idx = p * 512 + tid;          // 128 rows x 32 h8-chunks
        int row = idx >> 5, ch = idx & 31;
        *(h8*)(Hout + (long)(p0 + mq * 128 + row) * DHID + n0 + ch * 8) =
            *(const h8*)&cs[row * 264 + ch * 8];
      }
    }
  } else {
#pragma unroll
    for (int mq = 0; mq < 2; ++mq)
#pragma unroll
      for (int i = 0; i < 4; ++i)
#pragma unroll
        for (int reg = 0; reg < 4; ++reg) {
          int p = p0 + mq * 128 + wm * 64 + i * 16 + lq * 4 + reg;
          float wgt = pw[p];
          if (wgt != 0.f) {
            int tk = ptok[p];
            float* orow = out + (long)tk * DOUT + n0;
#pragma unroll
            for (int nq = 0; nq < 2; ++nq)
#pragma unroll
              for (int j = 0; j < 2; ++j)
                atomicAdd(&orow[nq * 128 + wn * 32 + j * 16 + ln15],
                          wgt * (acc[mq][i][nq][j][reg] + bj[nq][j]));
          }
        }
  }
}

extern "C" void kernel_launch(void* const* d_in, const int* in_sizes, int n_in,
                              void* d_out, int out_size, void* d_ws, size_t ws_size,
                              hipStream_t stream) {
  const float* x  = (const float*)d_in[0];
  const float* Wg = (const float*)d_in[1];
  const float* W1 = (const float*)d_in[2];
  const float* b1 = (const float*)d_in[3];
  const float* W2 = (const float*)d_in[4];
  const float* b2 = (const float*)d_in[5];
  float* out = (float*)d_out;
  char* ws = (char*)d_ws;

  size_t WT_OFF = 0;                                   // fp16 W^T (reused W1 then W2)
  size_t H_OFF  = WT_OFF + (size_t)NEXP * DHID * DIN * 2;   // 134,217,728
  size_t X_OFF  = H_OFF  + (size_t)PADMAX * DHID * 2;       // +167,772,160
  size_t TE_OFF = X_OFF  + (size_t)NTOK * DIN * 2;          // +16,777,216
  size_t TW_OFF = TE_OFF + (size_t)NPAIR * 4;
  size_t PT_OFF = TW_OFF + (size_t)NPAIR * 4;
  size_t PW_OFF = PT_OFF + (size_t)PADMAX * 4;
  size_t CT_OFF = PW_OFF + (size_t)PADMAX * 4;
  size_t END    = CT_OFF + 4096;
  if (ws_size < END) {
    fprintf(stderr, "kernel_launch: ws too small (%zu < %zu)\n", ws_size, END);
    return;
  }
  _Float16* Wt  = (_Float16*)(ws + WT_OFF);
  _Float16* H   = (_Float16*)(ws + H_OFF);
  _Float16* x16 = (_Float16*)(ws + X_OFF);
  int*   te   = (int*)(ws + TE_OFF);
  float* tw   = (float*)(ws + TW_OFF);
  int*   pt   = (int*)(ws + PT_OFF);
  float* pw   = (float*)(ws + PW_OFF);
  int*   ctrl = (int*)(ws + CT_OFF);

  k_init<<<NTOK * DIN / (256 * 4), 256, 0, stream>>>(out, x, x16, pt, pw, ctrl);
  k_gate<<<NTOK / 4, 256, 0, stream>>>(x, Wg, te, tw, ctrl);
  k_scan<<<1, 256, 0, stream>>>(ctrl);
  k_assign<<<NTOK / 256, 256, 0, stream>>>(te, tw, ctrl, pt, pw);

  // W1 [E][1024][4096] -> Wt [E][4096][1024] fp16
  k_transpose<<<dim3(DIN / 64, DHID / 64, NEXP), 256, 0, stream>>>(W1, Wt, DIN, DHID);
  // G1: works = 80 mt x 16 nb (nb-fastest)
  k_gemm<DIN, DHID, 1><<<dim3((DHID / 256) * MAXTILES), 512, 0, stream>>>(
      x16, Wt, b1, ctrl, pt, pw, H, nullptr);

  // W2 [E][4096][1024] -> Wt [E][1024][4096] fp16 (region reuse; stream-ordered)
  k_transpose<<<dim3(DHID / 64, DOUT / 64, NEXP), 256, 0, stream>>>(W2, Wt, DHID, DOUT);
  // G2: works = 80 mt x 4 nb (nb-fastest)
  k_gemm<DHID, DOUT, 0><<<dim3((DOUT / 256) * MAXTILES), 512, 0, stream>>>(
      H, Wt, b2, ctrl, pt, pw, nullptr, out);
}